// Round 1
// baseline (4176.262 us; speedup 1.0000x reference)
//
#include <hip/hip_runtime.h>

#define N_NODES 100000
#define E_EDGES 3200000
#define DESW 768
#define EMB 32

__device__ __forceinline__ float lrelu(float v) { return v > 0.f ? v : 0.01f * v; }

// ---------------------------------------------------------------------------
// Encoder: x = lrelu(concat(lrelu(des@Wd+bd), lrelu(tweet@Wt+bt),
//                            lrelu(num@Wn+bn), lrelu(cat@Wc+bc)) @ W_in + b_in)
// One wave per node; lanes 0-31 handle des, lanes 32-63 handle tweet.
// 768 cols / 32 lanes = 6 float4 per lane; butterfly-reduce 8 accumulators.
// ---------------------------------------------------------------------------
__global__ __launch_bounds__(256) void encode_kernel(
    const float* __restrict__ des, const float* __restrict__ tweet,
    const float* __restrict__ nump, const float* __restrict__ catp,
    const float* __restrict__ Wd, const float* __restrict__ bd,
    const float* __restrict__ Wt, const float* __restrict__ bt,
    const float* __restrict__ Wn, const float* __restrict__ bn,
    const float* __restrict__ Wc, const float* __restrict__ bc,
    const float* __restrict__ Win, const float* __restrict__ bin,
    float* __restrict__ x1)
{
    __shared__ float xblk[4][EMB];
    const int tid  = threadIdx.x;
    const int w    = tid >> 6;        // wave 0..3
    const int lane = tid & 63;
    const int half = lane >> 5;       // 0: des, 1: tweet
    const int l    = lane & 31;
    const int node = blockIdx.x * 4 + w;   // N divisible by 4

    const float*  src = half ? tweet : des;
    const float*  W   = half ? Wt : Wd;
    const float4* row = (const float4*)(src + (size_t)node * DESW);

    float acc[8] = {0, 0, 0, 0, 0, 0, 0, 0};
    #pragma unroll
    for (int j = 0; j < 6; ++j) {
        const int col4 = j * 32 + l;               // 192 float4 per row
        const float4 v = row[col4];
        const int col = col4 * 4;
        #pragma unroll
        for (int i = 0; i < 4; ++i) {
            const float e = (i == 0) ? v.x : (i == 1) ? v.y : (i == 2) ? v.z : v.w;
            const float4* wr = (const float4*)(W + (size_t)(col + i) * 8);
            const float4 w0 = wr[0], w1 = wr[1];
            acc[0] += e * w0.x; acc[1] += e * w0.y; acc[2] += e * w0.z; acc[3] += e * w0.w;
            acc[4] += e * w1.x; acc[5] += e * w1.y; acc[6] += e * w1.z; acc[7] += e * w1.w;
        }
    }
    // reduce over 32 lanes within each half-wave
    #pragma unroll
    for (int m = 16; m >= 1; m >>= 1) {
        #pragma unroll
        for (int q = 0; q < 8; ++q) acc[q] += __shfl_xor(acc[q], m, 32);
    }

    if (l < 8) {
        const float* bb = half ? bt : bd;
        xblk[w][half * 8 + l] = lrelu(acc[l] + bb[l]);
    } else if (l < 16) {
        const int q = l - 8;
        if (half == 0) {
            float s = bn[q];
            #pragma unroll
            for (int i = 0; i < 5; ++i) s += nump[(size_t)node * 5 + i] * Wn[i * 8 + q];
            xblk[w][16 + q] = lrelu(s);
        } else {
            float s = bc[q];
            #pragma unroll
            for (int i = 0; i < 3; ++i) s += catp[(size_t)node * 3 + i] * Wc[i * 8 + q];
            xblk[w][24 + q] = lrelu(s);
        }
    }
    __syncthreads();

    if (tid < 128) {
        const int wi = tid >> 5, k = tid & 31;
        const int nd = blockIdx.x * 4 + wi;
        float s = bin[k];
        #pragma unroll
        for (int j = 0; j < 32; ++j) s += xblk[wi][j] * Win[j * 32 + k];
        x1[(size_t)nd * 32 + k] = lrelu(s);
    }
}

// ---------------------------------------------------------------------------
// Edge scatter: sums[rel*N+dst][:] += x[src][:]  (+ counts on first pass).
// mean-aggr is linear, so we aggregate RAW x and apply W_rel afterwards.
// 8 threads per edge, one float4 (4 hw f32 atomics) each.
// ---------------------------------------------------------------------------
__global__ __launch_bounds__(256) void scatter_kernel(
    const int* __restrict__ ei, const int* __restrict__ et,
    const float* __restrict__ x, float* __restrict__ sums,
    float* __restrict__ cnt /* nullptr on second pass */)
{
    const int t = blockIdx.x * 256 + threadIdx.x;
    const int e = t >> 3, j = t & 7;
    if (e >= E_EDGES) return;
    const int s = ei[e];
    const int d = ei[E_EDGES + e];
    const int r = et[e];
    const float4 v = ((const float4*)(x + (size_t)s * 32))[j];
    float* dp = sums + ((size_t)r * N_NODES + d) * 32 + j * 4;
    unsafeAtomicAdd(dp + 0, v.x);
    unsafeAtomicAdd(dp + 1, v.y);
    unsafeAtomicAdd(dp + 2, v.z);
    unsafeAtomicAdd(dp + 3, v.w);
    if (cnt != nullptr && j == 0) unsafeAtomicAdd(&cnt[(size_t)r * N_NODES + d], 1.0f);
}

// ---------------------------------------------------------------------------
// RGCN node update (layer 1): x2 = mean0@Wrel0 + mean1@Wrel1 + x@Wroot + b
// One thread per (node, out-channel k); same-node loads broadcast in-wave.
// ---------------------------------------------------------------------------
__global__ __launch_bounds__(256) void node1_kernel(
    const float* __restrict__ x, const float* __restrict__ sums,
    const float* __restrict__ cnt,
    const float* __restrict__ Wrel, const float* __restrict__ Wroot,
    const float* __restrict__ b, float* __restrict__ xo)
{
    const int t = blockIdx.x * 256 + threadIdx.x;
    const int node = t >> 5, k = t & 31;
    if (node >= N_NODES) return;
    const float r0 = 1.0f / fmaxf(cnt[node], 1.0f);
    const float r1 = 1.0f / fmaxf(cnt[N_NODES + node], 1.0f);
    const float* s0 = sums + (size_t)node * 32;
    const float* s1 = sums + ((size_t)N_NODES + node) * 32;
    const float* xr = x + (size_t)node * 32;
    float acc = b[k];
    #pragma unroll
    for (int j = 0; j < 32; ++j) {
        acc += (s0[j] * r0) * Wrel[j * 32 + k]
             + (s1[j] * r1) * Wrel[1024 + j * 32 + k]
             + xr[j] * Wroot[j * 32 + k];
    }
    xo[(size_t)node * 32 + k] = acc;
}

// ---------------------------------------------------------------------------
// RGCN node update (layer 2) fused with output head:
// x3 = agg2 + x2@Wroot + b;  h = lrelu(x3@W1 + b1);  out = h@W2 + b2
// ---------------------------------------------------------------------------
__global__ __launch_bounds__(256) void node2_head_kernel(
    const float* __restrict__ x, const float* __restrict__ sums,
    const float* __restrict__ cnt,
    const float* __restrict__ Wrel, const float* __restrict__ Wroot,
    const float* __restrict__ b,
    const float* __restrict__ W1, const float* __restrict__ b1,
    const float* __restrict__ W2, const float* __restrict__ b2,
    float* __restrict__ out)
{
    __shared__ float xb[8][33];
    __shared__ float hb[8][33];
    const int tid = threadIdx.x;
    const int w = tid >> 5, k = tid & 31;
    const int node = blockIdx.x * 8 + w;   // N divisible by 8

    const float r0 = 1.0f / fmaxf(cnt[node], 1.0f);
    const float r1 = 1.0f / fmaxf(cnt[N_NODES + node], 1.0f);
    const float* s0 = sums + (size_t)node * 32;
    const float* s1 = sums + ((size_t)N_NODES + node) * 32;
    const float* xr = x + (size_t)node * 32;
    float acc = b[k];
    #pragma unroll
    for (int j = 0; j < 32; ++j) {
        acc += (s0[j] * r0) * Wrel[j * 32 + k]
             + (s1[j] * r1) * Wrel[1024 + j * 32 + k]
             + xr[j] * Wroot[j * 32 + k];
    }
    xb[w][k] = acc;
    __syncthreads();

    float h = b1[k];
    #pragma unroll
    for (int j = 0; j < 32; ++j) h += xb[w][j] * W1[j * 32 + k];
    hb[w][k] = lrelu(h);
    __syncthreads();

    if (k < 2) {
        float o = b2[k];
        #pragma unroll
        for (int j = 0; j < 32; ++j) o += hb[w][j] * W2[j * 2 + k];
        out[(size_t)node * 2 + k] = o;
    }
}

extern "C" void kernel_launch(void* const* d_in, const int* in_sizes, int n_in,
                              void* d_out, int out_size, void* d_ws, size_t ws_size,
                              hipStream_t stream)
{
    const float* des   = (const float*)d_in[0];
    const float* tweet = (const float*)d_in[1];
    const float* nump  = (const float*)d_in[2];
    const float* catp  = (const float*)d_in[3];
    const int*   ei    = (const int*)d_in[4];
    const int*   et    = (const int*)d_in[5];
    const float* Wd  = (const float*)d_in[6];  const float* bd  = (const float*)d_in[7];
    const float* Wt  = (const float*)d_in[8];  const float* bt  = (const float*)d_in[9];
    const float* Wn  = (const float*)d_in[10]; const float* bn  = (const float*)d_in[11];
    const float* Wc  = (const float*)d_in[12]; const float* bc  = (const float*)d_in[13];
    const float* Win = (const float*)d_in[14]; const float* bin = (const float*)d_in[15];
    const float* Wrel  = (const float*)d_in[16];
    const float* Wroot = (const float*)d_in[17];
    const float* brg   = (const float*)d_in[18];
    const float* W1 = (const float*)d_in[19]; const float* b1 = (const float*)d_in[20];
    const float* W2 = (const float*)d_in[21]; const float* b2 = (const float*)d_in[22];
    float* out = (float*)d_out;

    // workspace: x1[N*32] | x2[N*32] | sums[2N*32] | cnt[2N]   (52 MB total, f32)
    float* x1   = (float*)d_ws;
    float* x2   = x1 + (size_t)N_NODES * 32;
    float* sums = x2 + (size_t)N_NODES * 32;
    float* cnt  = sums + (size_t)2 * N_NODES * 32;

    hipMemsetAsync(sums, 0, (size_t)2 * N_NODES * 32 * sizeof(float), stream);
    hipMemsetAsync(cnt,  0, (size_t)2 * N_NODES * sizeof(float), stream);

    encode_kernel<<<N_NODES / 4, 256, 0, stream>>>(
        des, tweet, nump, catp, Wd, bd, Wt, bt, Wn, bn, Wc, bc, Win, bin, x1);

    scatter_kernel<<<E_EDGES * 8 / 256, 256, 0, stream>>>(ei, et, x1, sums, cnt);
    node1_kernel<<<N_NODES * 32 / 256, 256, 0, stream>>>(
        x1, sums, cnt, Wrel, Wroot, brg, x2);

    hipMemsetAsync(sums, 0, (size_t)2 * N_NODES * 32 * sizeof(float), stream);
    scatter_kernel<<<E_EDGES * 8 / 256, 256, 0, stream>>>(ei, et, x2, sums, nullptr);
    node2_head_kernel<<<N_NODES / 8, 256, 0, stream>>>(
        x2, sums, cnt, Wrel, Wroot, brg, W1, b1, W2, b2, out);
}

// Round 3
// 1810.135 us; speedup vs baseline: 2.3072x; 2.3072x over previous
//
#include <hip/hip_runtime.h>

#define N_NODES 100000
#define E_EDGES 3200000
#define NBINS   (2 * N_NODES)
#define DESW    768
#define EMB     32
#define CHUNK   1024
#define NSCAN1  ((NBINS + CHUNK - 1) / CHUNK)   // 196

__device__ __forceinline__ float lrelu(float v) { return v > 0.f ? v : 0.01f * v; }

// ---------------------------------------------------------------------------
// Encoder: x1 = lrelu(concat(lrelu(des@Wd+bd), lrelu(tweet@Wt+bt),
//                            lrelu(num@Wn+bn), lrelu(cat@Wc+bc)) @ W_in + b_in)
// Each wave: lanes 0-31 = des, lanes 32-63 = tweet, 4 NODES per wave so each
// W load is reused 4x (W working set 48KB > 32KB L1 -> reuse matters).
// Block = 4 waves = 16 nodes.
// ---------------------------------------------------------------------------
__global__ __launch_bounds__(256) void encode_kernel(
    const float* __restrict__ des, const float* __restrict__ tweet,
    const float* __restrict__ nump, const float* __restrict__ catp,
    const float* __restrict__ Wd, const float* __restrict__ bd,
    const float* __restrict__ Wt, const float* __restrict__ bt,
    const float* __restrict__ Wn, const float* __restrict__ bn,
    const float* __restrict__ Wc, const float* __restrict__ bc,
    const float* __restrict__ Win, const float* __restrict__ bin_,
    float* __restrict__ x1)
{
    __shared__ float xblk[16][33];
    const int tid  = threadIdx.x;
    const int w    = tid >> 6;
    const int lane = tid & 63;
    const int half = lane >> 5;       // 0: des, 1: tweet
    const int l    = lane & 31;
    const int nb   = blockIdx.x * 16 + w * 4;   // N divisible by 16

    const float* src = half ? tweet : des;
    const float* W   = half ? Wt : Wd;
    const float* bb  = half ? bt : bd;
    const float4* r0 = (const float4*)(src + (size_t)(nb + 0) * DESW);
    const float4* r1 = (const float4*)(src + (size_t)(nb + 1) * DESW);
    const float4* r2 = (const float4*)(src + (size_t)(nb + 2) * DESW);
    const float4* r3 = (const float4*)(src + (size_t)(nb + 3) * DESW);

    float acc[4][8] = {};
    #pragma unroll
    for (int j = 0; j < 6; ++j) {
        float4 v[4];
        v[0] = r0[j * 32 + l]; v[1] = r1[j * 32 + l];
        v[2] = r2[j * 32 + l]; v[3] = r3[j * 32 + l];
        const int colb = (j * 32 + l) * 4;
        #pragma unroll
        for (int i = 0; i < 4; ++i) {
            const float4* wr = (const float4*)(W + (size_t)(colb + i) * 8);
            const float4 w0 = wr[0], w1 = wr[1];
            #pragma unroll
            for (int m = 0; m < 4; ++m) {
                const float e = ((const float*)&v[m])[i];
                acc[m][0] += e * w0.x; acc[m][1] += e * w0.y;
                acc[m][2] += e * w0.z; acc[m][3] += e * w0.w;
                acc[m][4] += e * w1.x; acc[m][5] += e * w1.y;
                acc[m][6] += e * w1.z; acc[m][7] += e * w1.w;
            }
        }
    }
    #pragma unroll
    for (int s = 16; s >= 1; s >>= 1) {
        #pragma unroll
        for (int m = 0; m < 4; ++m) {
            #pragma unroll
            for (int q = 0; q < 8; ++q) acc[m][q] += __shfl_xor(acc[m][q], s, 32);
        }
    }
    if (l < 8) {
        #pragma unroll
        for (int m = 0; m < 4; ++m)
            xblk[w * 4 + m][half * 8 + l] = lrelu(acc[m][l] + bb[l]);
    }

    // num/cat: 16 nodes x 16 outputs = 256 work items, one per thread
    {
        const int nn = tid >> 4, q8 = tid & 15;
        const int node = blockIdx.x * 16 + nn;
        if (q8 < 8) {
            float s = bn[q8];
            #pragma unroll
            for (int i = 0; i < 5; ++i) s += nump[(size_t)node * 5 + i] * Wn[i * 8 + q8];
            xblk[nn][16 + q8] = lrelu(s);
        } else {
            const int q = q8 - 8;
            float s = bc[q];
            #pragma unroll
            for (int i = 0; i < 3; ++i) s += catp[(size_t)node * 3 + i] * Wc[i * 8 + q];
            xblk[nn][24 + q] = lrelu(s);
        }
    }
    __syncthreads();

    #pragma unroll
    for (int rep = 0; rep < 2; ++rep) {
        const int nn = (tid >> 5) + rep * 8;
        const int k  = tid & 31;
        float s = bin_[k];
        #pragma unroll
        for (int j = 0; j < 32; ++j) s += xblk[nn][j] * Win[j * 32 + k];
        x1[((size_t)blockIdx.x * 16 + nn) * 32 + k] = lrelu(s);
    }
}

// ---------------------------------------------------------------------------
// CSR build over bins = rel*N + dst (x-independent, built once, reused twice)
// ---------------------------------------------------------------------------
__global__ __launch_bounds__(256) void hist_kernel(
    const int* __restrict__ ei, const int* __restrict__ et, int* __restrict__ deg)
{
    const int e = blockIdx.x * 256 + threadIdx.x;
    if (e >= E_EDGES) return;
    const int d = ei[E_EDGES + e], r = et[e];
    atomicAdd(&deg[r * N_NODES + d], 1);
}

__global__ __launch_bounds__(256) void scan1_kernel(
    const int* __restrict__ deg, int* __restrict__ offs, int* __restrict__ bsums)
{
    __shared__ int sh[256];
    const int tid = threadIdx.x;
    const int i0 = blockIdx.x * CHUNK + tid * 4;
    int v[4]; int T = 0;
    #pragma unroll
    for (int i = 0; i < 4; ++i) {
        const int idx = i0 + i;
        v[i] = (idx < NBINS) ? deg[idx] : 0;
        T += v[i];
    }
    sh[tid] = T; __syncthreads();
    for (int off = 1; off < 256; off <<= 1) {
        const int u = (tid >= off) ? sh[tid - off] : 0;
        __syncthreads();
        sh[tid] += u;
        __syncthreads();
    }
    int run = sh[tid] - T;   // exclusive prefix of this thread's 4
    #pragma unroll
    for (int i = 0; i < 4; ++i) {
        const int idx = i0 + i;
        if (idx < NBINS) offs[idx] = run;
        run += v[i];
    }
    if (tid == 255) bsums[blockIdx.x] = sh[255];
}

__global__ __launch_bounds__(256) void scan2_kernel(int* __restrict__ bsums, int nb)
{
    __shared__ int sh[256];
    const int tid = threadIdx.x;
    const int T = (tid < nb) ? bsums[tid] : 0;
    sh[tid] = T; __syncthreads();
    for (int off = 1; off < 256; off <<= 1) {
        const int u = (tid >= off) ? sh[tid - off] : 0;
        __syncthreads();
        sh[tid] += u;
        __syncthreads();
    }
    if (tid < nb) bsums[tid] = sh[tid] - T;
}

__global__ __launch_bounds__(256) void scan3_kernel(
    int* __restrict__ offs, const int* __restrict__ bsums, int* __restrict__ cur)
{
    const int i = blockIdx.x * 256 + threadIdx.x;
    if (i < NBINS) {
        const int v = offs[i] + bsums[i / CHUNK];
        offs[i] = v;
        cur[i] = v;
    } else if (i == NBINS) {
        offs[NBINS] = E_EDGES;
    }
}

__global__ __launch_bounds__(256) void fill_kernel(
    const int* __restrict__ ei, const int* __restrict__ et,
    int* __restrict__ cur, int* __restrict__ srcs)
{
    const int e = blockIdx.x * 256 + threadIdx.x;
    if (e >= E_EDGES) return;
    const int s = ei[e], d = ei[E_EDGES + e], r = et[e];
    const int pos = atomicAdd(&cur[r * N_NODES + d], 1);
    srcs[pos] = s;
}

// ---------------------------------------------------------------------------
// Gather-reduce: mean[bin][:] = sum_{e in bin} x[srcs[e]][:] / max(deg,1)
// 8 threads per bin (one float4 each). x (12.8MB) is L3-resident; each edge
// read is a coalesced 128B row. No atomics.
// ---------------------------------------------------------------------------
__global__ __launch_bounds__(256) void gather_kernel(
    const int* __restrict__ offs, const int* __restrict__ srcs,
    const float* __restrict__ x, float* __restrict__ mean)
{
    const int t = blockIdx.x * 256 + threadIdx.x;
    const int bin = t >> 3, j = t & 7;
    if (bin >= NBINS) return;
    const int o0 = offs[bin], o1 = offs[bin + 1];
    float4 acc = {0.f, 0.f, 0.f, 0.f};
    for (int i = o0; i < o1; ++i) {
        const int s = srcs[i];
        const float4 v = ((const float4*)(x + (size_t)s * 32))[j];
        acc.x += v.x; acc.y += v.y; acc.z += v.z; acc.w += v.w;
    }
    const float inv = 1.0f / fmaxf((float)(o1 - o0), 1.0f);
    float4 o = {acc.x * inv, acc.y * inv, acc.z * inv, acc.w * inv};
    ((float4*)(mean + (size_t)bin * 32))[j] = o;
}

// ---------------------------------------------------------------------------
// RGCN node update (layer 1): x2 = mean0@Wrel0 + mean1@Wrel1 + x@Wroot + b
// ---------------------------------------------------------------------------
__global__ __launch_bounds__(256) void node1_kernel(
    const float* __restrict__ x, const float* __restrict__ mean,
    const float* __restrict__ Wrel, const float* __restrict__ Wroot,
    const float* __restrict__ b, float* __restrict__ xo)
{
    const int t = blockIdx.x * 256 + threadIdx.x;
    const int node = t >> 5, k = t & 31;
    if (node >= N_NODES) return;
    const float* s0 = mean + (size_t)node * 32;
    const float* s1 = mean + ((size_t)N_NODES + node) * 32;
    const float* xr = x + (size_t)node * 32;
    float acc = b[k];
    #pragma unroll
    for (int j = 0; j < 32; ++j) {
        acc += s0[j] * Wrel[j * 32 + k]
             + s1[j] * Wrel[1024 + j * 32 + k]
             + xr[j] * Wroot[j * 32 + k];
    }
    xo[(size_t)node * 32 + k] = acc;
}

// ---------------------------------------------------------------------------
// RGCN node update (layer 2) fused with output head
// ---------------------------------------------------------------------------
__global__ __launch_bounds__(256) void node2_head_kernel(
    const float* __restrict__ x, const float* __restrict__ mean,
    const float* __restrict__ Wrel, const float* __restrict__ Wroot,
    const float* __restrict__ b,
    const float* __restrict__ W1, const float* __restrict__ b1,
    const float* __restrict__ W2, const float* __restrict__ b2,
    float* __restrict__ out)
{
    __shared__ float xb[8][33];
    __shared__ float hb[8][33];
    const int tid = threadIdx.x;
    const int w = tid >> 5, k = tid & 31;
    const int node = blockIdx.x * 8 + w;   // N divisible by 8

    const float* s0 = mean + (size_t)node * 32;
    const float* s1 = mean + ((size_t)N_NODES + node) * 32;
    const float* xr = x + (size_t)node * 32;
    float acc = b[k];
    #pragma unroll
    for (int j = 0; j < 32; ++j) {
        acc += s0[j] * Wrel[j * 32 + k]
             + s1[j] * Wrel[1024 + j * 32 + k]
             + xr[j] * Wroot[j * 32 + k];
    }
    xb[w][k] = acc;
    __syncthreads();

    float h = b1[k];
    #pragma unroll
    for (int j = 0; j < 32; ++j) h += xb[w][j] * W1[j * 32 + k];
    hb[w][k] = lrelu(h);
    __syncthreads();

    if (k < 2) {
        float o = b2[k];
        #pragma unroll
        for (int j = 0; j < 32; ++j) o += hb[w][j] * W2[j * 2 + k];
        out[(size_t)node * 2 + k] = o;
    }
}

extern "C" void kernel_launch(void* const* d_in, const int* in_sizes, int n_in,
                              void* d_out, int out_size, void* d_ws, size_t ws_size,
                              hipStream_t stream)
{
    const float* des   = (const float*)d_in[0];
    const float* tweet = (const float*)d_in[1];
    const float* nump  = (const float*)d_in[2];
    const float* catp  = (const float*)d_in[3];
    const int*   ei    = (const int*)d_in[4];
    const int*   et    = (const int*)d_in[5];
    const float* Wd  = (const float*)d_in[6];  const float* bd  = (const float*)d_in[7];
    const float* Wt  = (const float*)d_in[8];  const float* bt  = (const float*)d_in[9];
    const float* Wn  = (const float*)d_in[10]; const float* bn  = (const float*)d_in[11];
    const float* Wc  = (const float*)d_in[12]; const float* bc  = (const float*)d_in[13];
    const float* Win = (const float*)d_in[14]; const float* bin_ = (const float*)d_in[15];
    const float* Wrel  = (const float*)d_in[16];
    const float* Wroot = (const float*)d_in[17];
    const float* brg   = (const float*)d_in[18];
    const float* W1 = (const float*)d_in[19]; const float* b1 = (const float*)d_in[20];
    const float* W2 = (const float*)d_in[21]; const float* b2 = (const float*)d_in[22];
    float* out = (float*)d_out;

    // workspace layout (all 16B-aligned):
    // x1[N*32] | x2[N*32] | mean[2N*32] | deg[2N] | offs[2N+1] | bsums[256] | cur[2N] | srcs[E]
    float* x1   = (float*)d_ws;
    float* x2   = x1 + (size_t)N_NODES * 32;
    float* mean = x2 + (size_t)N_NODES * 32;
    int* deg   = (int*)(mean + (size_t)NBINS * 32);
    int* offs  = deg + NBINS;
    int* bsums = offs + NBINS + 1;
    int* cur   = bsums + 256;
    int* srcs  = cur + NBINS;

    hipMemsetAsync(deg, 0, NBINS * sizeof(int), stream);

    encode_kernel<<<N_NODES / 16, 256, 0, stream>>>(
        des, tweet, nump, catp, Wd, bd, Wt, bt, Wn, bn, Wc, bc, Win, bin_, x1);

    // CSR build (once; topology is x-independent)
    hist_kernel<<<E_EDGES / 256, 256, 0, stream>>>(ei, et, deg);
    scan1_kernel<<<NSCAN1, 256, 0, stream>>>(deg, offs, bsums);
    scan2_kernel<<<1, 256, 0, stream>>>(bsums, NSCAN1);
    scan3_kernel<<<(NBINS + 256) / 256, 256, 0, stream>>>(offs, bsums, cur);
    fill_kernel<<<E_EDGES / 256, 256, 0, stream>>>(ei, et, cur, srcs);

    // layer 1
    gather_kernel<<<NBINS * 8 / 256, 256, 0, stream>>>(offs, srcs, x1, mean);
    node1_kernel<<<N_NODES * 32 / 256, 256, 0, stream>>>(x1, mean, Wrel, Wroot, brg, x2);

    // layer 2 + head
    gather_kernel<<<NBINS * 8 / 256, 256, 0, stream>>>(offs, srcs, x2, mean);
    node2_head_kernel<<<N_NODES / 8, 256, 0, stream>>>(
        x2, mean, Wrel, Wroot, brg, W1, b1, W2, b2, out);
}